// Round 9
// baseline (1028.188 us; speedup 1.0000x reference)
//
#include <hip/hip_runtime.h>
#include <hip/hip_bf16.h>

// Causal SDPA, B=4 H=16 S=2048 D=128, fp32 in/out, bf16 MFMA compute.
// R8 (resubmit; prior round died on GPU acquisition, never measured).
// Key-split waves -> 4 equal blocks/CU. R7 post-mortem: perfect balance
// at 2 blocks/CU changed nothing vs R4 (both ~6 waves/CU avg, 128-130us,
// no pipe >45%) -> latency-bound, need more independent streams/SIMD.
// Now: 1024 blocks, each = 256 thr / 4 waves on a 64-q-row item; wave =
// (rowpair rp, keyhalf kh): 32 rows x 2 subtiles (proven R4 economics) but
// only 32 of the tile's 64 keys -> per-wave work halves coherently (8 kf
// reads/16 QK MFMA, 8 vf/16 PV MFMA, 16 exp2), staging stays kreg[4]+
// vreg[4] (no R6 spill), LDS/block unchanged 35.8KB -> 4 blocks/CU = 16
// waves/CU FLAT. kh-partial oacc/l_run combined once per item via LDS
// scratch (amortized /33 tiles). Balance: block b takes items {b, 2047-b}
// = exactly 33 key-tiles for every block. launch_bounds(256,4) caps VGPR
// at 128 (halved sc/pfrag frees ~20 vs R7's 120).

#define SEQ 2048
#define DIM 128
#define BN 64
#define BHN 64
#define NITEMS 2048            // 64 bh x 32 half-qtiles (64 rows each)
#define KSTRIDE (DIM + 8)      // 136 shorts; 16B-aligned rows, 2-way banks
#define VSTRIDE (BN + 8)       // 72
#define M_FIXED 14.0f          // fixed softmax max in exp2 domain

typedef short bf16x8 __attribute__((ext_vector_type(8)));
typedef float f32x4 __attribute__((ext_vector_type(4)));

__device__ __forceinline__ short f2bf(float f) {
  union { float f; unsigned u; } v; v.f = f;
  return (short)((v.u + 0x8000u) >> 16);
}
__device__ __forceinline__ unsigned pack2(short lo, short hi) {
  return (unsigned)(unsigned short)lo | ((unsigned)(unsigned short)hi << 16);
}
__device__ __forceinline__ unsigned cvt_pk(float lo, float hi) {
  unsigned r;
  asm("v_cvt_pk_bf16_f32 %0, %1, %2" : "=v"(r) : "v"(lo), "v"(hi));
  return r;
}

// ---- pre-kernel: fp32 -> bf16 straight convert (K) ----
__global__ void conv_bf16(const float* __restrict__ src, short* __restrict__ dst) {
  size_t i = ((size_t)blockIdx.x * 256 + threadIdx.x) * 8;
  float4 a = *(const float4*)(src + i);
  float4 b = *(const float4*)(src + i + 4);
  bf16x8 f;
  f[0] = f2bf(a.x); f[1] = f2bf(a.y); f[2] = f2bf(a.z); f[3] = f2bf(a.w);
  f[4] = f2bf(b.x); f[5] = f2bf(b.y); f[6] = f2bf(b.z); f[7] = f2bf(b.w);
  *(bf16x8*)(dst + i) = f;
}

// ---- pre-kernel: V -> bf16 transposed per head: Vt[bh][d][key] ----
#define TKS 130
__global__ void trans_v(const float* __restrict__ Vg, short* __restrict__ Vt) {
  __shared__ short t[64 * TKS];          // 16,640 B
  const int kb = blockIdx.x * 64;
  const int bh = blockIdx.y;
  const int tid = threadIdx.x;
  const float* src = Vg + ((size_t)bh * SEQ + kb) * DIM;
  #pragma unroll
  for (int it = 0; it < 4; ++it) {
    int idx = it * 2048 + tid * 8;       // 64x128 / 8 per thread
    int row = idx >> 7, col = idx & 127; // key=row, d=col..col+7
    float4 a = *(const float4*)(src + (size_t)row * DIM + col);
    float4 b = *(const float4*)(src + (size_t)row * DIM + col + 4);
    unsigned* p = (unsigned*)&t[row * TKS + col];
    p[0] = pack2(f2bf(a.x), f2bf(a.y));
    p[1] = pack2(f2bf(a.z), f2bf(a.w));
    p[2] = pack2(f2bf(b.x), f2bf(b.y));
    p[3] = pack2(f2bf(b.z), f2bf(b.w));
  }
  __syncthreads();
  short* dst = Vt + (size_t)bh * DIM * SEQ + kb;
  const int k0 = (tid & 7) * 8;          // 8 keys per thread
  #pragma unroll
  for (int it = 0; it < 4; ++it) {
    int d = it * 32 + (tid >> 3);        // 32 d-rows per iter
    bf16x8 f;
    #pragma unroll
    for (int j = 0; j < 8; ++j) f[j] = t[(k0 + j) * TKS + d];
    *(bf16x8*)&dst[(size_t)d * SEQ + k0] = f;   // coalesced 128B per 8 lanes
  }
}

template <bool PRE>
__global__ __launch_bounds__(256, 4)
void fa_fwd(const float* __restrict__ Qg, const float* __restrict__ Kg,
            const float* __restrict__ Vg, const short* __restrict__ Kb,
            const short* __restrict__ Vt, float* __restrict__ Og) {
  __shared__ short ksh[BN * KSTRIDE];      // 17,408 B  [key][d]
  __shared__ short vsh[DIM * VSTRIDE];     // 18,432 B  [d][key]

  const int tid   = threadIdx.x;
  const int wave  = tid >> 6;
  const int kh    = wave >> 1;             // key-half (0: keys 0-31, 1: 32-63)
  const int rp    = wave & 1;              // row-pair (which 32 of 64 rows)
  const int lane  = tid & 63;
  const int quad  = lane >> 4;
  const int l16   = lane & 15;
  const float SCL = 0.08838834764831845f * 1.4426950408889634f;

  // staging index precompute: 4 chunks of 8 shorts per thread (256 threads)
  int krow[4], kcol[4], vd[4], vk[4];
  #pragma unroll
  for (int it = 0; it < 4; ++it) {
    int idx = it * 2048 + tid * 8;
    krow[it] = idx >> 7; kcol[it] = idx & 127;
    vd[it] = idx >> 6;   vk[it] = idx & 63;
  }

  #pragma unroll 1
  for (int round = 0; round < 2; ++round) {
    // paired schedule: block b handles items b and 2047-b; costs
    // (31-(b>>6))+1 and (b>>6)+1 key-tiles -> exactly 33 for EVERY block.
    const int item = round == 0 ? (int)blockIdx.x : (NITEMS - 1 - (int)blockIdx.x);
    const int h  = 31 - (item >> 6);
    const int bh = item & 63;
    const int qw = h * 64 + rp * 32;       // this wave's 32 q-rows
    const size_t base = (size_t)bh * SEQ * DIM;
    const int ntiles = h + 1;              // causal: keys 0 .. 64h+63

    // ---- Q fragments for both 16-row sub-tiles ----
    bf16x8 qf[2][4];
    #pragma unroll
    for (int s = 0; s < 2; ++s) {
      const float* qp = Qg + base + (size_t)(qw + s * 16 + l16) * DIM + quad * 8;
      #pragma unroll
      for (int kc = 0; kc < 4; ++kc) {
        float4 a = ((const float4*)(qp + kc * 32))[0];
        float4 b = ((const float4*)(qp + kc * 32))[1];
        bf16x8 f;
        f[0] = f2bf(a.x * SCL); f[1] = f2bf(a.y * SCL);
        f[2] = f2bf(a.z * SCL); f[3] = f2bf(a.w * SCL);
        f[4] = f2bf(b.x * SCL); f[5] = f2bf(b.y * SCL);
        f[6] = f2bf(b.z * SCL); f[7] = f2bf(b.w * SCL);
        qf[s][kc] = f;
      }
    }

    f32x4 oacc[2][8];
    #pragma unroll
    for (int s = 0; s < 2; ++s)
      #pragma unroll
      for (int i = 0; i < 8; ++i) oacc[s][i] = (f32x4){0.f, 0.f, 0.f, 0.f};
    float l_run[2] = {0.f, 0.f};

    const short* gKb = PRE ? (Kb + base) : nullptr;
    const short* gVt = PRE ? (Vt + (size_t)bh * DIM * SEQ) : nullptr;
    bf16x8 kreg[4], vreg[4];
    if constexpr (PRE) {
      #pragma unroll
      for (int it = 0; it < 4; ++it) {
        kreg[it] = *(const bf16x8*)&gKb[(size_t)krow[it] * DIM + kcol[it]];
        vreg[it] = *(const bf16x8*)&gVt[(size_t)vd[it] * SEQ + vk[it]];
      }
    }

    for (int kt = 0; kt < ntiles; ++kt) {
      const int kb = kt * BN;
      __syncthreads();

      if constexpr (PRE) {
        #pragma unroll
        for (int it = 0; it < 4; ++it) {
          *(bf16x8*)&ksh[krow[it] * KSTRIDE + kcol[it]] = kreg[it];
          *(bf16x8*)&vsh[vd[it] * VSTRIDE + vk[it]] = vreg[it];
        }
      } else {
        const float* gK = Kg + base + (size_t)kb * DIM;
        #pragma unroll
        for (int it = 0; it < 4; ++it) {
          const float4* p = (const float4*)(gK + (size_t)krow[it] * DIM + kcol[it]);
          float4 a = p[0], b = p[1];
          bf16x8 f;
          f[0] = f2bf(a.x); f[1] = f2bf(a.y); f[2] = f2bf(a.z); f[3] = f2bf(a.w);
          f[4] = f2bf(b.x); f[5] = f2bf(b.y); f[6] = f2bf(b.z); f[7] = f2bf(b.w);
          *(bf16x8*)&ksh[krow[it] * KSTRIDE + kcol[it]] = f;
        }
        const float* gV = Vg + base + (size_t)kb * DIM;
        int c = tid & 127, rbase = (tid >> 7) * 8;
        #pragma unroll
        for (int it = 0; it < 4; ++it) {
          int r0 = rbase + it * 16;
          bf16x8 f;
          #pragma unroll
          for (int j = 0; j < 8; ++j) f[j] = f2bf(gV[(size_t)(r0 + j) * DIM + c]);
          *(bf16x8*)&vsh[c * VSTRIDE + r0] = f;
        }
      }
      __syncthreads();

      if constexpr (PRE) {
        if (kt + 1 < ntiles) {
          const short* nK = gKb + (size_t)(kb + BN) * DIM;
          const short* nV = gVt + kb + BN;
          #pragma unroll
          for (int it = 0; it < 4; ++it) {
            kreg[it] = *(const bf16x8*)&nK[(size_t)krow[it] * DIM + kcol[it]];
            vreg[it] = *(const bf16x8*)&nV[(size_t)vd[it] * SEQ + vk[it]];
          }
        }
      }

      // waves whose 32 keys start beyond their last q-row skip compute
      // (barriers above stay block-uniform)
      const bool act = (kb + kh * 32 <= qw + 31);
      if (act) {
        // ---- QK^T swapped: mfma(K, Q) -> lane holds P^T[key][q=l16] ----
        // this wave's keys: kb + kh*32 + t*16 + quad*4 + r, t in {0,1}
        f32x4 sc[2][2];
        #pragma unroll
        for (int s = 0; s < 2; ++s)
          #pragma unroll
          for (int t = 0; t < 2; ++t)
            sc[s][t] = (f32x4){-M_FIXED, -M_FIXED, -M_FIXED, -M_FIXED};

        __builtin_amdgcn_s_setprio(1);
        #pragma unroll
        for (int t = 0; t < 2; ++t) {
          #pragma unroll
          for (int kc = 0; kc < 4; ++kc) {
            bf16x8 kf = *(const bf16x8*)&ksh[(kh * 32 + t * 16 + l16) * KSTRIDE + kc * 32 + quad * 8];
            sc[0][t] = __builtin_amdgcn_mfma_f32_16x16x32_bf16(kf, qf[0][kc], sc[0][t], 0, 0, 0);
            sc[1][t] = __builtin_amdgcn_mfma_f32_16x16x32_bf16(kf, qf[1][kc], sc[1][t], 0, 0, 0);
          }
        }
        __builtin_amdgcn_s_setprio(0);

        // ---- fixed-max softmax (exp2 domain); bias already in sc ----
        #pragma unroll
        for (int s = 0; s < 2; ++s) {
          const int qs = qw + s * 16;
          if (kb + kh * 32 + 31 <= qs) {
            #pragma unroll
            for (int t = 0; t < 2; ++t)
              #pragma unroll
              for (int r = 0; r < 4; ++r)
                sc[s][t][r] = exp2f(sc[s][t][r]);
          } else {
            const int qrow = qs + l16;
            #pragma unroll
            for (int t = 0; t < 2; ++t) {
              #pragma unroll
              for (int r = 0; r < 4; ++r) {
                int key = kb + kh * 32 + t * 16 + quad * 4 + r;
                sc[s][t][r] = (key <= qrow) ? exp2f(sc[s][t][r]) : 0.f;
              }
            }
          }
          l_run[s] += ((sc[s][0][0] + sc[s][0][1]) + (sc[s][0][2] + sc[s][0][3]))
                    + ((sc[s][1][0] + sc[s][1][1]) + (sc[s][1][2] + sc[s][1][3]));
        }

        // ---- build PV A-frag fully in-register (cvt_pk + permlane) ----
        bf16x8 pfrag[2];
        #pragma unroll
        for (int s = 0; s < 2; ++s) {
          unsigned alo = cvt_pk(sc[s][0][0], sc[s][0][1]);
          unsigned blo = cvt_pk(sc[s][0][2], sc[s][0][3]);
          unsigned ahi = cvt_pk(sc[s][1][0], sc[s][1][1]);
          unsigned bhi = cvt_pk(sc[s][1][2], sc[s][1][3]);
          auto xy  = __builtin_amdgcn_permlane32_swap(alo, ahi, false, false);
          auto w02 = __builtin_amdgcn_permlane16_swap(xy[0], xy[1], false, false);
          auto xy2 = __builtin_amdgcn_permlane32_swap(blo, bhi, false, false);
          auto w13 = __builtin_amdgcn_permlane16_swap(xy2[0], xy2[1], false, false);
          union { unsigned u[4]; bf16x8 v; } pu;
          pu.u[0] = w02[0]; pu.u[1] = w13[0];
          pu.u[2] = w02[1]; pu.u[3] = w13[1];
          pfrag[s] = pu.v;
        }

        // ---- PV over this wave's 32 keys; each vf feeds BOTH sub-tiles ----
        __builtin_amdgcn_s_setprio(1);
        #pragma unroll
        for (int dt = 0; dt < 8; ++dt) {
          bf16x8 vf = *(const bf16x8*)&vsh[(dt * 16 + l16) * VSTRIDE + kh * 32 + quad * 8];
          oacc[0][dt] = __builtin_amdgcn_mfma_f32_16x16x32_bf16(pfrag[0], vf, oacc[0][dt], 0, 0, 0);
          oacc[1][dt] = __builtin_amdgcn_mfma_f32_16x16x32_bf16(pfrag[1], vf, oacc[1][dt], 0, 0, 0);
        }
        __builtin_amdgcn_s_setprio(0);
      }
    }

    // ---- wave-local l reduce: lane -> row-total for q = l16 ----
    #pragma unroll
    for (int s = 0; s < 2; ++s) {
      l_run[s] += __shfl_xor(l_run[s], 16, 64);
      l_run[s] += __shfl_xor(l_run[s], 32, 64);
    }

    // ---- combine the two key-half waves via LDS scratch ----
    // rp=0 pair uses ksh (17,408B), rp=1 pair uses vsh (18,432B);
    // per lane 68 floats (16B-aligned stride): 64 oacc + 2 l_run.
    __syncthreads();                       // all tile reads done
    float* sp = (float*)(rp == 0 ? (void*)ksh : (void*)vsh) + lane * 68;
    if (kh == 1) {
      #pragma unroll
      for (int s = 0; s < 2; ++s)
        #pragma unroll
        for (int dt = 0; dt < 8; ++dt)
          *(f32x4*)&sp[(s * 8 + dt) * 4] = oacc[s][dt];
      sp[64] = l_run[0]; sp[65] = l_run[1];
    }
    __syncthreads();
    if (kh == 0) {
      #pragma unroll
      for (int s = 0; s < 2; ++s)
        #pragma unroll
        for (int dt = 0; dt < 8; ++dt) {
          f32x4 o = *(const f32x4*)&sp[(s * 8 + dt) * 4];
          oacc[s][dt] += o;
        }
      l_run[0] += sp[64]; l_run[1] += sp[65];

      #pragma unroll
      for (int s = 0; s < 2; ++s)
        #pragma unroll
        for (int r = 0; r < 4; ++r) {
          float inv = 1.0f / __shfl(l_run[s], quad * 4 + r, 64);
          float* op = Og + base + (size_t)(qw + s * 16 + quad * 4 + r) * DIM + l16;
          #pragma unroll
          for (int dt = 0; dt < 8; ++dt) op[dt * 16] = oacc[s][dt][r] * inv;
        }
    }
  }
}

extern "C" void kernel_launch(void* const* d_in, const int* in_sizes, int n_in,
                              void* d_out, int out_size, void* d_ws, size_t ws_size,
                              hipStream_t stream) {
  const float* Q = (const float*)d_in[0];
  const float* K = (const float*)d_in[1];
  const float* V = (const float*)d_in[2];
  float* O = (float*)d_out;
  const size_t elems = (size_t)BHN * SEQ * DIM;
  const size_t need = 2 * elems * sizeof(short);
  if (ws_size >= need) {
    short* Kb = (short*)d_ws;
    short* Vt = Kb + elems;
    conv_bf16<<<(int)(elems / 8 / 256), 256, 0, stream>>>(K, Kb);
    trans_v<<<dim3(SEQ / 64, BHN), 256, 0, stream>>>(V, Vt);
    fa_fwd<true><<<NITEMS / 2, 256, 0, stream>>>(Q, K, V, Kb, Vt, O);
  } else {
    fa_fwd<false><<<NITEMS / 2, 256, 0, stream>>>(Q, K, V, nullptr, nullptr, O);
  }
}

// Round 10
// 297.322 us; speedup vs baseline: 3.4582x; 3.4582x over previous
//
#include <hip/hip_runtime.h>
#include <hip/hip_bf16.h>

// Causal SDPA, B=4 H=16 S=2048 D=128, fp32 in/out, bf16 MFMA compute.
// R9: R7 base (measured 128us fa_fwd, 120 VGPR, no spill) + double-buffered
// K/V LDS with ONE barrier per key-tile. R8 post-mortem: launch_bounds(256,4)
// VGPR-capped at 64 arch regs (oacc alone is 64) -> 3.77GB spill traffic ->
// 857us; occupancy is NOT the lever at this register footprint (m214's ref
// attn hits ~900TF at the same 8 waves/CU). New structure: LDS writes for
// tile t+1 sit between QK^T(t) and PV(t) (overlap compute), one
// __syncthreads per tile instead of two. LDS 71,680B -> still 2 blocks/CU.
// Keeps R7's perfectly-balanced pairing (block b takes items {b,1023-b} =
// exactly 34 key-tiles each), swapped QK^T, in-register P via cvt_pk+
// permlane, fixed-max exp2 softmax, setprio, diagonal wave skip.

#define SEQ 2048
#define DIM 128
#define BM 128                 // per block (4 waves x 32 rows)
#define BN 64
#define BHN 64
#define NTILES 1024            // 16 qtiles x 64 bh
#define KSTRIDE (DIM + 8)      // 136 shorts; 16B-aligned rows, 2-way banks
#define VSTRIDE (BN + 8)       // 72
#define M_FIXED 14.0f          // fixed softmax max in exp2 domain

typedef short bf16x8 __attribute__((ext_vector_type(8)));
typedef float f32x4 __attribute__((ext_vector_type(4)));

__device__ __forceinline__ short f2bf(float f) {
  union { float f; unsigned u; } v; v.f = f;
  return (short)((v.u + 0x8000u) >> 16);
}
__device__ __forceinline__ unsigned pack2(short lo, short hi) {
  return (unsigned)(unsigned short)lo | ((unsigned)(unsigned short)hi << 16);
}
__device__ __forceinline__ unsigned cvt_pk(float lo, float hi) {
  unsigned r;
  asm("v_cvt_pk_bf16_f32 %0, %1, %2" : "=v"(r) : "v"(lo), "v"(hi));
  return r;
}

// ---- pre-kernel: fp32 -> bf16 straight convert (K) ----
__global__ void conv_bf16(const float* __restrict__ src, short* __restrict__ dst) {
  size_t i = ((size_t)blockIdx.x * 256 + threadIdx.x) * 8;
  float4 a = *(const float4*)(src + i);
  float4 b = *(const float4*)(src + i + 4);
  bf16x8 f;
  f[0] = f2bf(a.x); f[1] = f2bf(a.y); f[2] = f2bf(a.z); f[3] = f2bf(a.w);
  f[4] = f2bf(b.x); f[5] = f2bf(b.y); f[6] = f2bf(b.z); f[7] = f2bf(b.w);
  *(bf16x8*)(dst + i) = f;
}

// ---- pre-kernel: V -> bf16 transposed per head: Vt[bh][d][key] ----
#define TKS 130
__global__ void trans_v(const float* __restrict__ Vg, short* __restrict__ Vt) {
  __shared__ short t[64 * TKS];          // 16,640 B
  const int kb = blockIdx.x * 64;
  const int bh = blockIdx.y;
  const int tid = threadIdx.x;
  const float* src = Vg + ((size_t)bh * SEQ + kb) * DIM;
  #pragma unroll
  for (int it = 0; it < 4; ++it) {
    int idx = it * 2048 + tid * 8;       // 64x128 / 8 per thread
    int row = idx >> 7, col = idx & 127; // key=row, d=col..col+7
    float4 a = *(const float4*)(src + (size_t)row * DIM + col);
    float4 b = *(const float4*)(src + (size_t)row * DIM + col + 4);
    unsigned* p = (unsigned*)&t[row * TKS + col];
    p[0] = pack2(f2bf(a.x), f2bf(a.y));
    p[1] = pack2(f2bf(a.z), f2bf(a.w));
    p[2] = pack2(f2bf(b.x), f2bf(b.y));
    p[3] = pack2(f2bf(b.z), f2bf(b.w));
  }
  __syncthreads();
  short* dst = Vt + (size_t)bh * DIM * SEQ + kb;
  const int k0 = (tid & 7) * 8;          // 8 keys per thread
  #pragma unroll
  for (int it = 0; it < 4; ++it) {
    int d = it * 32 + (tid >> 3);        // 32 d-rows per iter
    bf16x8 f;
    #pragma unroll
    for (int j = 0; j < 8; ++j) f[j] = t[(k0 + j) * TKS + d];
    *(bf16x8*)&dst[(size_t)d * SEQ + k0] = f;   // coalesced 128B per 8 lanes
  }
}

template <bool PRE>
__global__ __launch_bounds__(256, 2)
void fa_fwd(const float* __restrict__ Qg, const float* __restrict__ Kg,
            const float* __restrict__ Vg, const short* __restrict__ Kb,
            const short* __restrict__ Vt, float* __restrict__ Og) {
  __shared__ short ksh[2][BN * KSTRIDE];   // 2 x 17,408 B  [key][d]
  __shared__ short vsh[2][DIM * VSTRIDE];  // 2 x 18,432 B  [d][key]

  const int tid   = threadIdx.x;
  const int wave  = tid >> 6;
  const int lane  = tid & 63;
  const int quad  = lane >> 4;
  const int l16   = lane & 15;
  const float SCL = 0.08838834764831845f * 1.4426950408889634f;

  // staging index precompute: 4 chunks of 8 shorts per thread (256 threads)
  int krow[4], kcol[4], vd[4], vk[4];
  #pragma unroll
  for (int it = 0; it < 4; ++it) {
    int idx = it * 2048 + tid * 8;
    krow[it] = idx >> 7; kcol[it] = idx & 127;
    vd[it] = idx >> 6;   vk[it] = idx & 63;
  }

  #pragma unroll 1
  for (int round = 0; round < 2; ++round) {
    // paired schedule: block b handles tile-items b and 1023-b ->
    // qtile pair sums to 15, total exactly 34 key-tiles for EVERY block.
    const int item = round == 0 ? (int)blockIdx.x : (NTILES - 1 - (int)blockIdx.x);
    const int qtile = 15 - (item >> 6);
    const int bh    = item & 63;
    const int qw = qtile * BM + wave * 32;   // this wave's 32 q-rows
    const size_t base = (size_t)bh * SEQ * DIM;
    const int ntiles = 2 * qtile + 2;        // >= 2 always

    // ---- Q fragments for both 16-row sub-tiles ----
    bf16x8 qf[2][4];
    #pragma unroll
    for (int s = 0; s < 2; ++s) {
      const float* qp = Qg + base + (size_t)(qw + s * 16 + l16) * DIM + quad * 8;
      #pragma unroll
      for (int kc = 0; kc < 4; ++kc) {
        float4 a = ((const float4*)(qp + kc * 32))[0];
        float4 b = ((const float4*)(qp + kc * 32))[1];
        bf16x8 f;
        f[0] = f2bf(a.x * SCL); f[1] = f2bf(a.y * SCL);
        f[2] = f2bf(a.z * SCL); f[3] = f2bf(a.w * SCL);
        f[4] = f2bf(b.x * SCL); f[5] = f2bf(b.y * SCL);
        f[6] = f2bf(b.z * SCL); f[7] = f2bf(b.w * SCL);
        qf[s][kc] = f;
      }
    }

    f32x4 oacc[2][8];
    #pragma unroll
    for (int s = 0; s < 2; ++s)
      #pragma unroll
      for (int i = 0; i < 8; ++i) oacc[s][i] = (f32x4){0.f, 0.f, 0.f, 0.f};
    float l_run[2] = {0.f, 0.f};

    const short* gKb = PRE ? (Kb + base) : nullptr;
    const short* gVt = PRE ? (Vt + (size_t)bh * DIM * SEQ) : nullptr;
    bf16x8 kreg[4], vreg[4];

    // ---- prologue: tile 0 -> buf0; prefetch tile 1 -> regs ----
    if constexpr (PRE) {
      #pragma unroll
      for (int it = 0; it < 4; ++it) {
        kreg[it] = *(const bf16x8*)&gKb[(size_t)krow[it] * DIM + kcol[it]];
        vreg[it] = *(const bf16x8*)&gVt[(size_t)vd[it] * SEQ + vk[it]];
      }
      #pragma unroll
      for (int it = 0; it < 4; ++it) {
        *(bf16x8*)&ksh[0][krow[it] * KSTRIDE + kcol[it]] = kreg[it];
        *(bf16x8*)&vsh[0][vd[it] * VSTRIDE + vk[it]] = vreg[it];
      }
      const short* nK = gKb + (size_t)BN * DIM;
      const short* nV = gVt + BN;
      #pragma unroll
      for (int it = 0; it < 4; ++it) {
        kreg[it] = *(const bf16x8*)&nK[(size_t)krow[it] * DIM + kcol[it]];
        vreg[it] = *(const bf16x8*)&nV[(size_t)vd[it] * SEQ + vk[it]];
      }
    } else {
      const float* gK = Kg + base;
      #pragma unroll
      for (int it = 0; it < 4; ++it) {
        const float4* p = (const float4*)(gK + (size_t)krow[it] * DIM + kcol[it]);
        float4 a = p[0], b = p[1];
        bf16x8 f;
        f[0] = f2bf(a.x); f[1] = f2bf(a.y); f[2] = f2bf(a.z); f[3] = f2bf(a.w);
        f[4] = f2bf(b.x); f[5] = f2bf(b.y); f[6] = f2bf(b.z); f[7] = f2bf(b.w);
        *(bf16x8*)&ksh[0][krow[it] * KSTRIDE + kcol[it]] = f;
      }
      const float* gV = Vg + base;
      int c = tid & 127, rbase = (tid >> 7) * 8;
      #pragma unroll
      for (int it = 0; it < 4; ++it) {
        int r0 = rbase + it * 16;
        bf16x8 f;
        #pragma unroll
        for (int j = 0; j < 8; ++j) f[j] = f2bf(gV[(size_t)(r0 + j) * DIM + c]);
        *(bf16x8*)&vsh[0][c * VSTRIDE + r0] = f;
      }
    }
    __syncthreads();

    for (int kt = 0; kt < ntiles; ++kt) {
      const int kb = kt * BN;
      const int cur = kt & 1;
      const bool act = (kb <= qw + 31);

      // ---- QK^T swapped: mfma(K, Q) -> lane holds P^T[key][q=l16] ----
      f32x4 sc[2][4];
      if (act) {
        #pragma unroll
        for (int s = 0; s < 2; ++s)
          #pragma unroll
          for (int t = 0; t < 4; ++t)
            sc[s][t] = (f32x4){-M_FIXED, -M_FIXED, -M_FIXED, -M_FIXED};

        __builtin_amdgcn_s_setprio(1);
        #pragma unroll
        for (int t = 0; t < 4; ++t) {
          #pragma unroll
          for (int kc = 0; kc < 4; ++kc) {
            bf16x8 kf = *(const bf16x8*)&ksh[cur][(t * 16 + l16) * KSTRIDE + kc * 32 + quad * 8];
            sc[0][t] = __builtin_amdgcn_mfma_f32_16x16x32_bf16(kf, qf[0][kc], sc[0][t], 0, 0, 0);
            sc[1][t] = __builtin_amdgcn_mfma_f32_16x16x32_bf16(kf, qf[1][kc], sc[1][t], 0, 0, 0);
          }
        }
        __builtin_amdgcn_s_setprio(0);
      }

      // ---- stage tile kt+1 into buf[cur^1] (overlaps softmax/PV below);
      //      then issue global loads for tile kt+2 ----
      if constexpr (PRE) {
        if (kt + 1 < ntiles) {
          #pragma unroll
          for (int it = 0; it < 4; ++it) {
            *(bf16x8*)&ksh[cur ^ 1][krow[it] * KSTRIDE + kcol[it]] = kreg[it];
            *(bf16x8*)&vsh[cur ^ 1][vd[it] * VSTRIDE + vk[it]] = vreg[it];
          }
          if (kt + 2 < ntiles) {
            const short* nK = gKb + (size_t)(kb + 2 * BN) * DIM;
            const short* nV = gVt + kb + 2 * BN;
            #pragma unroll
            for (int it = 0; it < 4; ++it) {
              kreg[it] = *(const bf16x8*)&nK[(size_t)krow[it] * DIM + kcol[it]];
              vreg[it] = *(const bf16x8*)&nV[(size_t)vd[it] * SEQ + vk[it]];
            }
          }
        }
      } else {
        if (kt + 1 < ntiles) {
          const float* gK = Kg + base + (size_t)(kb + BN) * DIM;
          #pragma unroll
          for (int it = 0; it < 4; ++it) {
            const float4* p = (const float4*)(gK + (size_t)krow[it] * DIM + kcol[it]);
            float4 a = p[0], b = p[1];
            bf16x8 f;
            f[0] = f2bf(a.x); f[1] = f2bf(a.y); f[2] = f2bf(a.z); f[3] = f2bf(a.w);
            f[4] = f2bf(b.x); f[5] = f2bf(b.y); f[6] = f2bf(b.z); f[7] = f2bf(b.w);
            *(bf16x8*)&ksh[cur ^ 1][krow[it] * KSTRIDE + kcol[it]] = f;
          }
          const float* gV = Vg + base + (size_t)(kb + BN) * DIM;
          int c = tid & 127, rbase = (tid >> 7) * 8;
          #pragma unroll
          for (int it = 0; it < 4; ++it) {
            int r0 = rbase + it * 16;
            bf16x8 f;
            #pragma unroll
            for (int j = 0; j < 8; ++j) f[j] = f2bf(gV[(size_t)(r0 + j) * DIM + c]);
            *(bf16x8*)&vsh[cur ^ 1][c * VSTRIDE + r0] = f;
          }
        }
      }

      if (act) {
        // ---- fixed-max softmax (exp2 domain); bias already in sc ----
        // swapped layout: key = kb + t*16 + quad*4 + r, qrow = qs + l16
        #pragma unroll
        for (int s = 0; s < 2; ++s) {
          const int qs = qw + s * 16;
          if (kb + 63 <= qs) {
            #pragma unroll
            for (int t = 0; t < 4; ++t)
              #pragma unroll
              for (int r = 0; r < 4; ++r)
                sc[s][t][r] = exp2f(sc[s][t][r]);
          } else {
            const int qrow = qs + l16;
            #pragma unroll
            for (int t = 0; t < 4; ++t) {
              #pragma unroll
              for (int r = 0; r < 4; ++r) {
                int key = kb + t * 16 + quad * 4 + r;
                sc[s][t][r] = (key <= qrow) ? exp2f(sc[s][t][r]) : 0.f;
              }
            }
          }
          l_run[s] += (((sc[s][0][0] + sc[s][0][1]) + (sc[s][0][2] + sc[s][0][3]))
                     + ((sc[s][1][0] + sc[s][1][1]) + (sc[s][1][2] + sc[s][1][3])))
                    + (((sc[s][2][0] + sc[s][2][1]) + (sc[s][2][2] + sc[s][2][3]))
                     + ((sc[s][3][0] + sc[s][3][1]) + (sc[s][3][2] + sc[s][3][3])));
        }

        // ---- build PV A-frags fully in-register (cvt_pk + permlane) ----
        bf16x8 pfrag[2][2];
        #pragma unroll
        for (int s = 0; s < 2; ++s) {
          #pragma unroll
          for (int kc = 0; kc < 2; ++kc) {
            unsigned alo = cvt_pk(sc[s][2 * kc][0],     sc[s][2 * kc][1]);
            unsigned blo = cvt_pk(sc[s][2 * kc][2],     sc[s][2 * kc][3]);
            unsigned ahi = cvt_pk(sc[s][2 * kc + 1][0], sc[s][2 * kc + 1][1]);
            unsigned bhi = cvt_pk(sc[s][2 * kc + 1][2], sc[s][2 * kc + 1][3]);
            auto xy  = __builtin_amdgcn_permlane32_swap(alo, ahi, false, false);
            auto w02 = __builtin_amdgcn_permlane16_swap(xy[0], xy[1], false, false);
            auto xy2 = __builtin_amdgcn_permlane32_swap(blo, bhi, false, false);
            auto w13 = __builtin_amdgcn_permlane16_swap(xy2[0], xy2[1], false, false);
            union { unsigned u[4]; bf16x8 v; } pu;
            pu.u[0] = w02[0]; pu.u[1] = w13[0];
            pu.u[2] = w02[1]; pu.u[3] = w13[1];
            pfrag[s][kc] = pu.v;
          }
        }

        // ---- PV: each V-frag read feeds BOTH sub-tiles ----
        __builtin_amdgcn_s_setprio(1);
        #pragma unroll
        for (int kc = 0; kc < 2; ++kc) {
          #pragma unroll
          for (int dt = 0; dt < 8; ++dt) {
            bf16x8 vf = *(const bf16x8*)&vsh[cur][(dt * 16 + l16) * VSTRIDE + kc * 32 + quad * 8];
            oacc[0][dt] = __builtin_amdgcn_mfma_f32_16x16x32_bf16(pfrag[0][kc], vf, oacc[0][dt], 0, 0, 0);
            oacc[1][dt] = __builtin_amdgcn_mfma_f32_16x16x32_bf16(pfrag[1][kc], vf, oacc[1][dt], 0, 0, 0);
          }
        }
        __builtin_amdgcn_s_setprio(0);
      }

      // one barrier per tile: fences this tile's reads of buf[cur] from
      // next iter's writes, and this iter's writes of buf[cur^1] from
      // next iter's reads.
      __syncthreads();
    }

    // ---- epilogue: l_run lives at q=l16; reduce across quads, then
    // redistribute to the PV output row layout (row = quad*4 + r) ----
    #pragma unroll
    for (int s = 0; s < 2; ++s) {
      l_run[s] += __shfl_xor(l_run[s], 16, 64);
      l_run[s] += __shfl_xor(l_run[s], 32, 64);
    }

    #pragma unroll
    for (int s = 0; s < 2; ++s)
      #pragma unroll
      for (int r = 0; r < 4; ++r) {
        float inv = 1.0f / __shfl(l_run[s], quad * 4 + r, 64);
        float* op = Og + base + (size_t)(qw + s * 16 + quad * 4 + r) * DIM + l16;
        #pragma unroll
        for (int dt = 0; dt < 8; ++dt) op[dt * 16] = oacc[s][dt][r] * inv;
      }
  }
}

extern "C" void kernel_launch(void* const* d_in, const int* in_sizes, int n_in,
                              void* d_out, int out_size, void* d_ws, size_t ws_size,
                              hipStream_t stream) {
  const float* Q = (const float*)d_in[0];
  const float* K = (const float*)d_in[1];
  const float* V = (const float*)d_in[2];
  float* O = (float*)d_out;
  const size_t elems = (size_t)BHN * SEQ * DIM;
  const size_t need = 2 * elems * sizeof(short);
  if (ws_size >= need) {
    short* Kb = (short*)d_ws;
    short* Vt = Kb + elems;
    conv_bf16<<<(int)(elems / 8 / 256), 256, 0, stream>>>(K, Kb);
    trans_v<<<dim3(SEQ / 64, BHN), 256, 0, stream>>>(V, Vt);
    fa_fwd<true><<<NTILES / 2, 256, 0, stream>>>(Q, K, V, Kb, Vt, O);
  } else {
    fa_fwd<false><<<NTILES / 2, 256, 0, stream>>>(Q, K, V, nullptr, nullptr, O);
  }
}